// Round 5
// baseline (393.006 us; speedup 1.0000x reference)
//
#include <hip/hip_runtime.h>
#include <hip/hip_fp16.h>
#include <math.h>

#define VOCAB 100000
#define HID 256
#define BATCH 4096
#define BN_EPS 1e-5f
#define TPB1 512      // tokens per block in k1 (4 waves x 128 tokens)

// ws layout (in floats)
#define WS_SEGSUM 0
#define WS_COUNTS (BATCH * HID)            // 1048576
#define WS_COLSUM (WS_COUNTS + BATCH)
#define WS_COLSQ  (WS_COLSUM + HID)
#define WS_ZERO_FLOATS (WS_COLSQ + HID)    // 1053184 floats; zero-filled by k0
#define WS_EMB16_OFF_BYTES ((size_t)WS_ZERO_FLOATS * 4)   // 16B-aligned
#define WS_FP16_BYTES_NEEDED (WS_EMB16_OFF_BYTES + (size_t)VOCAB * HID * 2)

// ---------------------------------------------------------------------------
// k0: emb fp32 -> fp16 table in ws; also zeroes the accumulator region.
// Byte-bound floor: ~170 MB traffic ≈ 27 us.
// ---------------------------------------------------------------------------
__global__ __launch_bounds__(256) void k0_convert_zero(
    const float* __restrict__ emb, __half* __restrict__ emb16,
    float4* __restrict__ zws, int n4, int nz4)
{
    int i = blockIdx.x * 256 + threadIdx.x;
    if (i < nz4) zws[i] = make_float4(0.f, 0.f, 0.f, 0.f);
    if (i >= n4) return;
    float4 v = reinterpret_cast<const float4*>(emb)[i];
    __half2 a = __halves2half2(__float2half_rn(v.x), __float2half_rn(v.y));
    __half2 b = __halves2half2(__float2half_rn(v.z), __float2half_rn(v.w));
    uint2 o;
    o.x = __builtin_bit_cast(unsigned int, a);
    o.y = __builtin_bit_cast(unsigned int, b);
    reinterpret_cast<uint2*>(emb16)[i] = o;
}

// ---------------------------------------------------------------------------
// k1 v3 (fp16 table, paired loads): half-wave h (lanes 32h..32h+31) covers
// the FULL 512B row of token i+h, 16B/lane (dwordx4). One load instruction
// delivers 2 tokens -> half the load-instr count of v2, 16 tokens in flight
// per iteration. Segment run tracking is per-lane (uniform within each
// half-wave); flushes are exec-masked and rare (~1% of pairs). Both halves
// flushing the same segment is safe: lanes l and l+32 atomicAdd the same
// 8 floats (device-scope atomics).
// ---------------------------------------------------------------------------
__global__ __launch_bounds__(256) void k1_gather_fp16(
    const int* __restrict__ token_ids, const int* __restrict__ segment_ids,
    const __half* __restrict__ emb16, float* __restrict__ seg_sum,
    float* __restrict__ counts, int T)
{
    __shared__ int s_tok[TPB1];
    __shared__ int s_seg[TPB1];
    const int tid = threadIdx.x;
    const int t0  = blockIdx.x * TPB1;
    const int n   = min(TPB1, T - t0);
    if (n <= 0) return;
    for (int i = tid; i < n; i += 256) {
        s_tok[i] = token_ids[t0 + i];
        s_seg[i] = segment_ids[t0 + i];
    }
    __syncthreads();

    const int wave = tid >> 6;
    const int lane = tid & 63;
    const int half = lane >> 5;       // which token of the pair
    const int sub  = lane & 31;       // which 16B chunk of the 512B row
    const int per  = TPB1 / 4;
    const int start = wave * per;
    const int end   = min(start + per, n);
    if (start >= end) return;

    const uint4* __restrict__ embv = reinterpret_cast<const uint4*>(emb16);
    float acc[8] = {0.f, 0.f, 0.f, 0.f, 0.f, 0.f, 0.f, 0.f};
    int cur    = s_seg[min(start + half, n - 1)];
    int runlen = 0;

    // flush this lane's accumulator into seg_sum[cur] (exec-masked caller)
#define K1_FLUSH() do {                                                        \
        float* p = &seg_sum[(size_t)cur * HID + sub * 8];                      \
        atomicAdd(p + 0, acc[0]); atomicAdd(p + 1, acc[1]);                    \
        atomicAdd(p + 2, acc[2]); atomicAdd(p + 3, acc[3]);                    \
        atomicAdd(p + 4, acc[4]); atomicAdd(p + 5, acc[5]);                    \
        atomicAdd(p + 6, acc[6]); atomicAdd(p + 7, acc[7]);                    \
        if (sub == 0) atomicAdd(&counts[cur], (float)runlen);                  \
        acc[0] = acc[1] = acc[2] = acc[3] = 0.f;                               \
        acc[4] = acc[5] = acc[6] = acc[7] = 0.f;                               \
        runlen = 0;                                                            \
    } while (0)

#define K1_PROC(ii, u) do {                                                    \
        int seg = s_seg[ii];            /* per-lane (uniform per half) */      \
        if (seg != cur) { K1_FLUSH(); cur = seg; }                             \
        float2 f;                                                              \
        f = __half22float2(__builtin_bit_cast(__half2, (u).x));                \
        acc[0] += f.x; acc[1] += f.y;                                          \
        f = __half22float2(__builtin_bit_cast(__half2, (u).y));                \
        acc[2] += f.x; acc[3] += f.y;                                          \
        f = __half22float2(__builtin_bit_cast(__half2, (u).z));                \
        acc[4] += f.x; acc[5] += f.y;                                          \
        f = __half22float2(__builtin_bit_cast(__half2, (u).w));                \
        acc[6] += f.x; acc[7] += f.y;                                          \
        runlen++;                                                              \
    } while (0)

    int i = start;
    const int endp = start + ((end - start) & ~15);   // 8 pairs (16 tok)/iter
    for (; i < endp; i += 16) {
        uint4 u0 = embv[(size_t)s_tok[i +  0 + half] * 32 + sub];
        uint4 u1 = embv[(size_t)s_tok[i +  2 + half] * 32 + sub];
        uint4 u2 = embv[(size_t)s_tok[i +  4 + half] * 32 + sub];
        uint4 u3 = embv[(size_t)s_tok[i +  6 + half] * 32 + sub];
        uint4 u4 = embv[(size_t)s_tok[i +  8 + half] * 32 + sub];
        uint4 u5 = embv[(size_t)s_tok[i + 10 + half] * 32 + sub];
        uint4 u6 = embv[(size_t)s_tok[i + 12 + half] * 32 + sub];
        uint4 u7 = embv[(size_t)s_tok[i + 14 + half] * 32 + sub];
        K1_PROC(i +  0 + half, u0);
        K1_PROC(i +  2 + half, u1);
        K1_PROC(i +  4 + half, u2);
        K1_PROC(i +  6 + half, u3);
        K1_PROC(i +  8 + half, u4);
        K1_PROC(i + 10 + half, u5);
        K1_PROC(i + 12 + half, u6);
        K1_PROC(i + 14 + half, u7);
    }
    for (; i + 1 < end; i += 2) {                     // pair tail
        uint4 u = embv[(size_t)s_tok[i + half] * 32 + sub];
        K1_PROC(i + half, u);
    }
    if (i < end && half == 0) {                       // odd single token
        uint4 u = embv[(size_t)s_tok[i] * 32 + sub];
        K1_PROC(i, u);
    }
    K1_FLUSH();                                       // all lanes
#undef K1_PROC
#undef K1_FLUSH
}

// ---------------------------------------------------------------------------
// k1 (fp32 fallback, only if ws too small for the fp16 table).
// ---------------------------------------------------------------------------
__global__ __launch_bounds__(256) void k1_gather_fp32(
    const int* __restrict__ token_ids, const int* __restrict__ segment_ids,
    const float* __restrict__ emb, float* __restrict__ seg_sum,
    float* __restrict__ counts, int T)
{
    __shared__ int s_tok[TPB1];
    __shared__ int s_seg[TPB1];
    const int tid = threadIdx.x;
    const int t0  = blockIdx.x * TPB1;
    const int n   = min(TPB1, T - t0);
    if (n <= 0) return;
    for (int i = tid; i < n; i += 256) {
        s_tok[i] = token_ids[t0 + i];
        s_seg[i] = segment_ids[t0 + i];
    }
    __syncthreads();

    const int wave = tid >> 6;
    const int lane = tid & 63;
    const int per  = TPB1 / 4;
    const int start = wave * per;
    const int end   = min(start + per, n);
    if (start >= end) return;

    const float4* __restrict__ embv = reinterpret_cast<const float4*>(emb);
    float4 acc = make_float4(0.f, 0.f, 0.f, 0.f);
    int cur = s_seg[start];
    int runlen = 0;

#define K1_FLUSH() do {                                                        \
        float* p = &seg_sum[(size_t)cur * HID + lane * 4];                     \
        atomicAdd(p + 0, acc.x); atomicAdd(p + 1, acc.y);                      \
        atomicAdd(p + 2, acc.z); atomicAdd(p + 3, acc.w);                      \
        if (lane == 0) atomicAdd(&counts[cur], (float)runlen);                 \
        acc = make_float4(0.f, 0.f, 0.f, 0.f); runlen = 0;                     \
    } while (0)

#define K1_PROC(ii, v) do {                                                    \
        int seg = s_seg[ii];                                                   \
        if (seg != cur) { K1_FLUSH(); cur = seg; }                             \
        acc.x += (v).x; acc.y += (v).y; acc.z += (v).z; acc.w += (v).w;        \
        runlen++;                                                              \
    } while (0)

    const int m4 = start + ((end - start) & ~3);
    for (int i = start; i < m4; i += 4) {
        float4 a0 = embv[(size_t)s_tok[i + 0] * 64 + lane];
        float4 a1 = embv[(size_t)s_tok[i + 1] * 64 + lane];
        float4 a2 = embv[(size_t)s_tok[i + 2] * 64 + lane];
        float4 a3 = embv[(size_t)s_tok[i + 3] * 64 + lane];
        K1_PROC(i + 0, a0); K1_PROC(i + 1, a1);
        K1_PROC(i + 2, a2); K1_PROC(i + 3, a3);
    }
    for (int i = m4; i < end; ++i) {
        float4 a = embv[(size_t)s_tok[i] * 64 + lane];
        K1_PROC(i, a);
    }
    K1_FLUSH();
#undef K1_PROC
#undef K1_FLUSH
}

// ---------------------------------------------------------------------------
// k2: h = (seg_sum/max(counts,1)) @ W1^T + b1, fused BN column partials.
// 256 blocks x 16 rows; 4x4 micro-tile per thread; ~10 us (DS-cycle bound).
// hout aliases seg_sum (rows staged to LDS first; blocks own disjoint rows).
// ---------------------------------------------------------------------------
#define KT2 32
__global__ __launch_bounds__(256) void k2_gemm_bn(
    const float* seg_sum, const float* __restrict__ counts,
    const float* __restrict__ W1, const float* __restrict__ b1,
    float* hout, float* __restrict__ colsum, float* __restrict__ colsq,
    float* __restrict__ out)
{
    __shared__ float s_bow[16][HID];          // 16 KB
    __shared__ float s_w1t[KT2][HID + 1];     // ~33 KB, k-major transposed
    __shared__ float s_cs[HID];
    __shared__ float s_cq[HID];
    const int tid = threadIdx.x;
    const int b0  = blockIdx.x * 16;

    if (blockIdx.x == 0 && tid == 0) out[0] = 0.f;   // k5 runs after k2
    s_cs[tid] = 0.f;
    s_cq[tid] = 0.f;

    const float4* ss4 = reinterpret_cast<const float4*>(seg_sum + (size_t)b0 * HID);
#pragma unroll
    for (int p = 0; p < 4; ++p) {
        int f  = p * 256 + tid;
        int r  = f >> 6, k4 = f & 63;
        float inv = 1.f / fmaxf(counts[b0 + r], 1.f);
        float4 v = ss4[f];
        v.x *= inv; v.y *= inv; v.z *= inv; v.w *= inv;
        *reinterpret_cast<float4*>(&s_bow[r][k4 * 4]) = v;
    }

    const int jr = tid >> 3;
    const int q  = tid & 7;
    const float4* __restrict__ W1v = reinterpret_cast<const float4*>(W1);

    float4 pre[8];
#pragma unroll
    for (int pass = 0; pass < 8; ++pass)
        pre[pass] = W1v[(size_t)(pass * 32 + jr) * 64 + q];

    const int cg = tid & 63;
    const int rg = tid >> 6;

    float acc[4][4];
    {
        float4 bj = reinterpret_cast<const float4*>(b1)[cg];
#pragma unroll
        for (int r = 0; r < 4; ++r) {
            acc[r][0] = bj.x; acc[r][1] = bj.y;
            acc[r][2] = bj.z; acc[r][3] = bj.w;
        }
    }

    for (int kt = 0; kt < HID / KT2; ++kt) {
        __syncthreads();
#pragma unroll
        for (int pass = 0; pass < 8; ++pass) {
            int j = pass * 32 + jr;
            float4 w = pre[pass];
            int kl = q * 4;
            s_w1t[kl + 0][j] = w.x;
            s_w1t[kl + 1][j] = w.y;
            s_w1t[kl + 2][j] = w.z;
            s_w1t[kl + 3][j] = w.w;
        }
        __syncthreads();
        if (kt + 1 < HID / KT2) {
#pragma unroll
            for (int pass = 0; pass < 8; ++pass)
                pre[pass] = W1v[(size_t)(pass * 32 + jr) * 64 + (kt + 1) * 8 + q];
        }
#pragma unroll
        for (int ks = 0; ks < 8; ++ks) {
            const int kg = kt * KT2 + ks * 4;
            const int kl = ks * 4;
            float4 bb0 = *reinterpret_cast<const float4*>(&s_bow[rg * 4 + 0][kg]);
            float4 bb1 = *reinterpret_cast<const float4*>(&s_bow[rg * 4 + 1][kg]);
            float4 bb2 = *reinterpret_cast<const float4*>(&s_bow[rg * 4 + 2][kg]);
            float4 bb3 = *reinterpret_cast<const float4*>(&s_bow[rg * 4 + 3][kg]);
            float4 w0 = *reinterpret_cast<const float4*>(&s_w1t[kl + 0][cg * 4]);
            float4 w1 = *reinterpret_cast<const float4*>(&s_w1t[kl + 1][cg * 4]);
            float4 w2 = *reinterpret_cast<const float4*>(&s_w1t[kl + 2][cg * 4]);
            float4 w3 = *reinterpret_cast<const float4*>(&s_w1t[kl + 3][cg * 4]);
#define K2_ROW(r, bb)                                                          \
            acc[r][0] = fmaf(bb.x, w0.x, fmaf(bb.y, w1.x,                      \
                        fmaf(bb.z, w2.x, fmaf(bb.w, w3.x, acc[r][0]))));       \
            acc[r][1] = fmaf(bb.x, w0.y, fmaf(bb.y, w1.y,                      \
                        fmaf(bb.z, w2.y, fmaf(bb.w, w3.y, acc[r][1]))));       \
            acc[r][2] = fmaf(bb.x, w0.z, fmaf(bb.y, w1.z,                      \
                        fmaf(bb.z, w2.z, fmaf(bb.w, w3.z, acc[r][2]))));       \
            acc[r][3] = fmaf(bb.x, w0.w, fmaf(bb.y, w1.w,                      \
                        fmaf(bb.z, w2.w, fmaf(bb.w, w3.w, acc[r][3]))));
            K2_ROW(0, bb0)
            K2_ROW(1, bb1)
            K2_ROW(2, bb2)
            K2_ROW(3, bb3)
#undef K2_ROW
        }
    }

#pragma unroll
    for (int r = 0; r < 4; ++r) {
        float4 v;
        v.x = acc[r][0]; v.y = acc[r][1]; v.z = acc[r][2]; v.w = acc[r][3];
        *reinterpret_cast<float4*>(
            &hout[(size_t)(b0 + rg * 4 + r) * HID + cg * 4]) = v;
    }
#pragma unroll
    for (int c = 0; c < 4; ++c) {
        float ps  = ((acc[0][c] + acc[1][c]) + (acc[2][c] + acc[3][c]));
        float psq = ((acc[0][c] * acc[0][c] + acc[1][c] * acc[1][c])
                   + (acc[2][c] * acc[2][c] + acc[3][c] * acc[3][c]));
        atomicAdd(&s_cs[cg * 4 + c], ps);
        atomicAdd(&s_cq[cg * 4 + c], psq);
    }
    __syncthreads();
    atomicAdd(&colsum[tid], s_cs[tid]);
    atomicAdd(&colsq[tid], s_cq[tid]);
}

// ---------------------------------------------------------------------------
// k5: BN finalize (folded) + apply + ReLU + logits + BCE loss.
// ---------------------------------------------------------------------------
__global__ __launch_bounds__(256) void k5_bn_relu_logits_loss(
    const float* __restrict__ hmat,
    const float* __restrict__ colsum, const float* __restrict__ colsq,
    const float* __restrict__ gamma, const float* __restrict__ beta,
    const float* __restrict__ W2, const float* __restrict__ b2,
    const float* __restrict__ labels, float* __restrict__ out)
{
    __shared__ float s_loss[4];
    const int tid  = threadIdx.x;
    const int w    = tid >> 6;
    const int lane = tid & 63;
    const int b0   = blockIdx.x * 16 + w * 4;

    const int j0 = lane, j1 = lane + 64, j2 = lane + 128, j3 = lane + 192;

#define BN_SS(jj, sc, sh) \
    { float mu = colsum[jj] * (1.f / BATCH); \
      float vr = colsq[jj] * (1.f / BATCH) - mu * mu; \
      sc = gamma[jj] * rsqrtf(vr + BN_EPS); \
      sh = beta[jj] - mu * sc; }
    float sc0, sh0, sc1, sh1, sc2, sh2, sc3, sh3;
    BN_SS(j0, sc0, sh0); BN_SS(j1, sc1, sh1);
    BN_SS(j2, sc2, sh2); BN_SS(j3, sc3, sh3);
#undef BN_SS

    const float w0 = W2[j0], w1 = W2[j1], w2v = W2[j2], w3 = W2[j3];
    const float bias2 = b2[0];

    float bce_acc = 0.f;
#pragma unroll
    for (int rr = 0; rr < 4; ++rr) {
        const int b = b0 + rr;
        const float* hr = hmat + (size_t)b * HID;
        float h0 = hr[j0], h1 = hr[j1], h2 = hr[j2], h3 = hr[j3];
        float s = 0.f;
        s += fmaxf(fmaf(h0, sc0, sh0), 0.f) * w0;
        s += fmaxf(fmaf(h1, sc1, sh1), 0.f) * w1;
        s += fmaxf(fmaf(h2, sc2, sh2), 0.f) * w2v;
        s += fmaxf(fmaf(h3, sc3, sh3), 0.f) * w3;
#pragma unroll
        for (int off = 32; off > 0; off >>= 1)
            s += __shfl_down(s, off, 64);
        if (lane == 0) {
            float z = s + bias2;
            out[1 + b] = z;
            float lb = labels[b];
            bce_acc += fmaxf(z, 0.f) - z * lb + log1pf(expf(-fabsf(z)));
        }
    }
    if (lane == 0) s_loss[w] = bce_acc;
    __syncthreads();
    if (tid == 0) {
        float t = (s_loss[0] + s_loss[1]) + (s_loss[2] + s_loss[3]);
        atomicAdd(&out[0], t * (1.f / BATCH));
    }
}

// ---------------------------------------------------------------------------
extern "C" void kernel_launch(void* const* d_in, const int* in_sizes, int n_in,
                              void* d_out, int out_size, void* d_ws, size_t ws_size,
                              hipStream_t stream)
{
    const int*   token_ids   = (const int*)d_in[0];
    const int*   segment_ids = (const int*)d_in[1];
    const float* labels      = (const float*)d_in[2];
    const float* emb         = (const float*)d_in[3];
    const float* W1          = (const float*)d_in[4];
    const float* b1          = (const float*)d_in[5];
    const float* gamma       = (const float*)d_in[6];
    const float* beta        = (const float*)d_in[7];
    const float* W2          = (const float*)d_in[8];
    const float* b2          = (const float*)d_in[9];
    float* out = (float*)d_out;
    float* ws  = (float*)d_ws;

    float* seg_sum = ws + WS_SEGSUM;   // reused as h after k2
    float* counts  = ws + WS_COUNTS;
    float* colsum  = ws + WS_COLSUM;
    float* colsq   = ws + WS_COLSQ;

    const int T = in_sizes[0];
    const int g1 = (T + TPB1 - 1) / TPB1;

    if (ws_size >= WS_FP16_BYTES_NEEDED) {
        __half* emb16 = (__half*)((char*)d_ws + WS_EMB16_OFF_BYTES);
        const int n4  = VOCAB * HID / 4;
        const int nz4 = WS_ZERO_FLOATS / 4;
        k0_convert_zero<<<(n4 + 255) / 256, 256, 0, stream>>>(
            emb, emb16, (float4*)d_ws, n4, nz4);
        k1_gather_fp16<<<g1, 256, 0, stream>>>(token_ids, segment_ids, emb16,
                                               seg_sum, counts, T);
    } else {
        hipMemsetAsync(d_ws, 0, (size_t)WS_ZERO_FLOATS * sizeof(float), stream);
        k1_gather_fp32<<<g1, 256, 0, stream>>>(token_ids, segment_ids, emb,
                                               seg_sum, counts, T);
    }
    k2_gemm_bn<<<BATCH / 16, 256, 0, stream>>>(
        seg_sum, counts, W1, b1, /*hout=*/seg_sum, colsum, colsq, out);
    k5_bn_relu_logits_loss<<<BATCH / 16, 256, 0, stream>>>(
        seg_sum, colsum, colsq, gamma, beta, W2, b2, labels, out);
}